// Round 1
// baseline (25.473 us; speedup 1.0000x reference)
//
#include <hip/hip_runtime.h>
#include <hip/hip_bf16.h>

// Problem: B=32, T=1024, D=512, x float32 (B,T,D) viewed flat as per-batch
// row-major M[D][T].  Row 0 = padding, rows 1..D-1 = signal.
//   norm[t]      = sum_{d=1..D-1} |M[d][t]|
//   one_minus[t] = 1 / (1 + exp(M[0][t] - norm[t]))      (= 1 - sigmoid(pad-norm))
//   out[0][t]    = M[0][t] * (1 + |padding_amount|)
//   out[d][t]    = M[d][t] * one_minus[t]                 (d >= 1)
//
// Strategy: single pass over HBM.  Block of 512 threads (8 waves) owns a
// [512 rows x 128 cols] tile.  wave (slice) s covers rows [64s, 64s+64);
// each lane holds 2 adjacent columns -> 64 float2 = 128 floats cached in
// VGPRs (fully unrolled, static indexing).  Per-column |.|-partials reduced
// through LDS, then registers are scaled and stored.  1 read + 1 write.

#define BB 32
#define TT 1024
#define DD 512

constexpr int TB     = 128;           // columns per block
constexpr int SLICES = 8;             // waves per block
constexpr int ROWS   = DD / SLICES;   // 64 rows per wave

__global__ __launch_bounds__(512, 2) void padding_bottleneck_kernel(
    const float* __restrict__ x,
    const float* __restrict__ padding_amount,
    float* __restrict__ out)
{
    const int blk   = blockIdx.x;          // 0..255
    const int b     = blk >> 3;            // / (TT/TB)
    const int tile  = blk & 7;             // % (TT/TB)
    const int lane  = threadIdx.x & 63;
    const int slice = threadIdx.x >> 6;    // 0..7 (== wave id)
    const int c0    = lane * 2;            // column within tile (covers c0, c0+1)
    const int t0    = tile * TB + c0;      // global column

    const size_t batch_off = (size_t)b * DD * TT;
    const float* src = x   + batch_off + (size_t)slice * ROWS * TT + t0;
    float*       dst = out + batch_off + (size_t)slice * ROWS * TT + t0;

    // ---- pass 1: load tile slice into registers, accumulate |.| per column
    float2 v[ROWS];
    float s0 = 0.f, s1 = 0.f;
#pragma unroll
    for (int j = 0; j < ROWS; ++j) {
        v[j] = *reinterpret_cast<const float2*>(src + (size_t)j * TT);
        s0 += fabsf(v[j].x);
        s1 += fabsf(v[j].y);
    }

    __shared__ float psum[SLICES][TB];
    __shared__ float padv[TB];

    if (slice == 0) {
        // row 0 (d=0) is the padding row: exclude from the signal norm,
        // publish its value for the sigmoid argument.
        s0 -= fabsf(v[0].x);
        s1 -= fabsf(v[0].y);
        padv[c0]     = v[0].x;
        padv[c0 + 1] = v[0].y;
    }
    psum[slice][c0]     = s0;
    psum[slice][c0 + 1] = s1;
    __syncthreads();

    // ---- per-column weight (each thread redundantly for its 2 columns)
    float n0 = 0.f, n1 = 0.f;
#pragma unroll
    for (int s = 0; s < SLICES; ++s) {
        n0 += psum[s][c0];
        n1 += psum[s][c0 + 1];
    }
    // one_minus = 1 - sigmoid(pad - norm) = 1 / (1 + exp(pad - norm))
    const float om0 = 1.f / (1.f + __expf(padv[c0]     - n0) * 0.f + expf(padv[c0]     - n0));
    const float om1 = 1.f / (1.f + __expf(padv[c0 + 1] - n1) * 0.f + expf(padv[c0 + 1] - n1));

    const float scale = 1.f + fabsf(padding_amount[0]);

    // ---- pass 2: scale cached registers, store
#pragma unroll
    for (int j = 0; j < ROWS; ++j) {
        float m0 = om0, m1 = om1;
        if (slice == 0 && j == 0) { m0 = scale; m1 = scale; }
        float2 o;
        o.x = v[j].x * m0;
        o.y = v[j].y * m1;
        *reinterpret_cast<float2*>(dst + (size_t)j * TT) = o;
    }
}

extern "C" void kernel_launch(void* const* d_in, const int* in_sizes, int n_in,
                              void* d_out, int out_size, void* d_ws, size_t ws_size,
                              hipStream_t stream)
{
    const float* x  = (const float*)d_in[0];
    const float* pa = (const float*)d_in[1];
    float* out      = (float*)d_out;

    // grid: one block per (batch, 128-column tile) = 32 * 8 = 256 blocks
    dim3 grid(BB * (TT / TB));
    dim3 block(SLICES * 64);
    padding_bottleneck_kernel<<<grid, block, 0, stream>>>(x, pa, out);
}

// Round 2
// 25.052 us; speedup vs baseline: 1.0168x; 1.0168x over previous
//
#include <hip/hip_runtime.h>
#include <hip/hip_bf16.h>

// Problem: B=32, T=1024, D=512, x float32 (B,T,D) viewed flat as per-batch
// row-major M[D][T].  Row 0 = padding, rows 1..D-1 = signal.
//   norm[t]      = sum_{d=1..D-1} |M[d][t]|
//   one_minus[t] = 1 / (1 + exp(M[0][t] - norm[t]))      (= 1 - sigmoid(pad-norm))
//   out[0][t]    = M[0][t] * (1 + |padding_amount|)
//   out[d][t]    = M[d][t] * one_minus[t]                 (d >= 1)
//
// R2 strategy: single HBM pass, float4 everywhere, 2 blocks/CU.
//   Block = 512 threads (8 waves), tile = 512 rows x 64 cols.
//   Lane mapping: cg = lane&15 -> 4 adjacent cols (float4), rg = lane>>4 ->
//   16-row group.  Each thread caches 16 float4 = 64 floats in VGPRs
//   (static unroll).  |.|-partials: shfl_xor(16,32) across row-groups, one
//   LDS row per wave, then per-column weight, scale registers, store float4.

#define BB 32
#define TT 1024
#define DD 512

constexpr int TB    = 64;             // columns per block tile
constexpr int WAVES = 8;              // waves per block
constexpr int RPW   = DD / WAVES;     // 64 rows per wave
constexpr int R     = RPW / 4;        // 16 rows per thread (4 row-groups/wave)

__global__ __launch_bounds__(512, 4) void padding_bottleneck_kernel(
    const float* __restrict__ x,
    const float* __restrict__ padding_amount,
    float* __restrict__ out)
{
    const int blk  = blockIdx.x;           // 0..511
    const int b    = blk >> 4;             // batch (32)
    const int tile = blk & 15;             // 16 column-tiles per batch
    const int lane = threadIdx.x & 63;
    const int wav  = threadIdx.x >> 6;     // 0..7
    const int cg   = lane & 15;            // column group
    const int rg   = lane >> 4;            // row group 0..3
    const int c0   = cg * 4;               // col within tile
    const int t0   = tile * TB + c0;       // global col
    const int r0   = wav * RPW + rg * R;   // first row owned by this thread

    const size_t base = (size_t)b * DD * TT + (size_t)r0 * TT + t0;
    const float* src = x + base;
    float*       dst = out + base;

    // ---- pass 1: load 16 float4 into registers, per-column |.| partials
    float4 v[R];
    float s0 = 0.f, s1 = 0.f, s2 = 0.f, s3 = 0.f;
#pragma unroll
    for (int j = 0; j < R; ++j) {
        v[j] = *reinterpret_cast<const float4*>(src + (size_t)j * TT);
        s0 += fabsf(v[j].x); s1 += fabsf(v[j].y);
        s2 += fabsf(v[j].z); s3 += fabsf(v[j].w);
    }

    __shared__ float psum[WAVES][TB];
    __shared__ float padv[TB];

    const bool has_pad = (wav == 0 && rg == 0);   // this thread's j==0 is row d=0
    if (has_pad) {
        s0 -= fabsf(v[0].x); s1 -= fabsf(v[0].y);
        s2 -= fabsf(v[0].z); s3 -= fabsf(v[0].w);
        *reinterpret_cast<float4*>(&padv[c0]) = v[0];
    }

    // ---- fold the 4 row-groups of this wave (lanes ^16, ^32)
    s0 += __shfl_xor(s0, 16); s1 += __shfl_xor(s1, 16);
    s2 += __shfl_xor(s2, 16); s3 += __shfl_xor(s3, 16);
    s0 += __shfl_xor(s0, 32); s1 += __shfl_xor(s1, 32);
    s2 += __shfl_xor(s2, 32); s3 += __shfl_xor(s3, 32);

    if (rg == 0) {
        float4 t = make_float4(s0, s1, s2, s3);
        *reinterpret_cast<float4*>(&psum[wav][c0]) = t;
    }
    __syncthreads();

    // ---- per-column weight (redundantly per thread for its 4 columns)
    float n0 = 0.f, n1 = 0.f, n2 = 0.f, n3 = 0.f;
#pragma unroll
    for (int s = 0; s < WAVES; ++s) {
        float4 p = *reinterpret_cast<const float4*>(&psum[s][c0]);
        n0 += p.x; n1 += p.y; n2 += p.z; n3 += p.w;
    }
    const float4 pv = *reinterpret_cast<const float4*>(&padv[c0]);
    const float om0 = 1.f / (1.f + expf(pv.x - n0));
    const float om1 = 1.f / (1.f + expf(pv.y - n1));
    const float om2 = 1.f / (1.f + expf(pv.z - n2));
    const float om3 = 1.f / (1.f + expf(pv.w - n3));
    const float scale = 1.f + fabsf(padding_amount[0]);

    // ---- pass 2: scale cached registers, store float4
#pragma unroll
    for (int j = 0; j < R; ++j) {
        float4 o;
        if (has_pad && j == 0) {
            o.x = v[0].x * scale; o.y = v[0].y * scale;
            o.z = v[0].z * scale; o.w = v[0].w * scale;
        } else {
            o.x = v[j].x * om0; o.y = v[j].y * om1;
            o.z = v[j].z * om2; o.w = v[j].w * om3;
        }
        *reinterpret_cast<float4*>(dst + (size_t)j * TT) = o;
    }
}

extern "C" void kernel_launch(void* const* d_in, const int* in_sizes, int n_in,
                              void* d_out, int out_size, void* d_ws, size_t ws_size,
                              hipStream_t stream)
{
    const float* x  = (const float*)d_in[0];
    const float* pa = (const float*)d_in[1];
    float* out      = (float*)d_out;

    // one block per (batch, 64-col tile): 32 * 16 = 512 blocks = 2 per CU
    dim3 grid(BB * (TT / TB));
    dim3 block(WAVES * 64);
    padding_bottleneck_kernel<<<grid, block, 0, stream>>>(x, pa, out);
}